// Round 8
// baseline (63258.258 us; speedup 1.0000x reference)
//
#include <hip/hip_runtime.h>
#include <hip/hip_bf16.h>

typedef __hip_bfloat16 bf16;

#define NB   32
#define TE   600
#define TD   600
#define TGT  80
#define PREN 256
#define HID  512
#define ATTD 128
#define LF   32
#define LK   31
#define PH   512

__device__ __forceinline__ float b2f(bf16 x){ return __bfloat162float(x); }

__device__ __forceinline__ void ld8bf(const bf16* p, float* o){
  const uint4 u = *(const uint4*)p;
  o[0]=__uint_as_float(u.x<<16); o[1]=__uint_as_float(u.x&0xFFFF0000u);
  o[2]=__uint_as_float(u.y<<16); o[3]=__uint_as_float(u.y&0xFFFF0000u);
  o[4]=__uint_as_float(u.z<<16); o[5]=__uint_as_float(u.z&0xFFFF0000u);
  o[6]=__uint_as_float(u.w<<16); o[7]=__uint_as_float(u.w&0xFFFF0000u);
}

__device__ __forceinline__ void ld8f(const float* p, float* o){
  float4 a=*(const float4*)p, b=*(const float4*)(p+4);
  o[0]=a.x;o[1]=a.y;o[2]=a.z;o[3]=a.w;
  o[4]=b.x;o[5]=b.y;o[6]=b.z;o[7]=b.w;
}

__device__ __forceinline__ float dot8(const float* w, const float* z){
  return w[0]*z[0]+w[1]*z[1]+w[2]*z[2]+w[3]*z[3]
       + w[4]*z[4]+w[5]*z[5]+w[6]*z[6]+w[7]*z[7];
}

__device__ __forceinline__ float sigm(float x){ return 1.f/(1.f+__expf(-x)); }
__device__ __forceinline__ float tanhfast(float x){
  float e = __expf(2.f*x);
  return 1.f - 2.f/(e+1.f);
}

// ---------------- fp32 -> bf16 weight conversion -----------------
__global__ __launch_bounds__(256) void k_w2b(const float* __restrict__ s,
    bf16* __restrict__ d, int n)
{
  int i=(blockIdx.x*256+threadIdx.x)*4;
  int stride=gridDim.x*256*4;
  for (; i<n; i+=stride){
    float4 v=*(const float4*)(s+i);
    d[i  ]=__float2bfloat16(v.x);
    d[i+1]=__float2bfloat16(v.y);
    d[i+2]=__float2bfloat16(v.z);
    d[i+3]=__float2bfloat16(v.w);
  }
}

// ---------------- prenet: XS[t][b][256] (bf16) -----------------
__global__ __launch_bounds__(256) void k_prenet(const float* __restrict__ dec,
    const float* __restrict__ w1, const float* __restrict__ b1,
    const float* __restrict__ w2, const float* __restrict__ b2,
    bf16* __restrict__ XS)
{
  int t = blockIdx.x, tid = threadIdx.x;
  __shared__ __align__(16) float fr[NB*TGT];
  __shared__ __align__(16) float h1[NB*PREN];
  for (int i=tid;i<NB*TGT;i+=256){
    int b=i/TGT,c=i%TGT;
    fr[b*TGT+c] = (t==0)?0.f:dec[((size_t)b*TD+(t-1))*TGT+c];
  }
  __syncthreads();
  {
    int oc=tid; float bb=b1[oc];
    const float* wr = w1 + (size_t)oc*TGT;
    for (int b=0;b<NB;b++){
      float acc=bb;
      for (int k=0;k<TGT;k+=8){
        float wv[8]; ld8f(wr+k,wv);
        acc += dot8(wv, fr + b*TGT + k);
      }
      h1[b*PREN+oc]=fmaxf(acc,0.f);
    }
  }
  __syncthreads();
  {
    int oc=tid; float bb=b2[oc];
    const float* wr = w2 + (size_t)oc*PREN;
    for (int b=0;b<NB;b++){
      float acc=bb;
      for (int k=0;k<PREN;k+=8){
        float wv[8]; ld8f(wr+k,wv);
        acc += dot8(wv, h1 + b*PREN + k);
      }
      XS[((size_t)t*NB+b)*PREN+oc]=__float2bfloat16(fmaxf(acc,0.f));
    }
  }
}

// ---------------- proc_mem: PM[b][t][128] (bf16) -----------------
__global__ __launch_bounds__(256) void k_procmem(const float* __restrict__ enc,
    const float* __restrict__ mw, const float* __restrict__ mb, bf16* __restrict__ PM)
{
  int t=blockIdx.x, tid=threadIdx.x;
  __shared__ __align__(16) float xe[16*HID];
  int a = tid & 127, bh = tid >> 7;
  float bb = mb[a];
  const float* wr = mw + (size_t)a*HID;
  for (int half=0; half<2; half++){
    __syncthreads();
    for (int i=tid;i<16*HID;i+=256){
      int bl=i>>9, h=i&511;
      xe[i] = enc[((size_t)(half*16+bl)*TE + t)*HID + h];
    }
    __syncthreads();
    for (int bl=bh*8; bl<bh*8+8; bl++){
      float acc=bb;
      for (int k=0;k<HID;k+=8){
        float wv[8]; ld8f(wr+k,wv);
        acc += dot8(wv, xe + bl*HID + k);
      }
      PM[((size_t)(half*16+bl)*TE + t)*ATTD + a] = __float2bfloat16(acc);
    }
  }
}

// ---------------- phase BC: E-assembly + softmax + ctx + mel(t-1) ---------
// grid 160: blk<128: (b=blk>>2, k4=blk&3) E+softmax+ctx-slice
//           blk in [128,160): mel block, b = blk-128
__global__ __launch_bounds__(256) void k_bc(
    const float* __restrict__ AH, const bf16* __restrict__ PM,
    const bf16* __restrict__ LOC, const float* __restrict__ enc,
    const float* __restrict__ qw, const float* __restrict__ vw,
    float* __restrict__ W, float* __restrict__ WCUM, float* __restrict__ CTXw,
    const float* __restrict__ DHp, const float* __restrict__ CTXp,
    const float* __restrict__ projw, float* __restrict__ MEL, int t)
{
  int blk=blockIdx.x, tid=threadIdx.x;
  if (blk>=128){
    // ---- mel(t-1): reads DH(t-1), CTX(t-1) (both stable this phase) ----
    if (t==0) return;
    int b = blk-128;
    const float* dh = DHp + b*HID;
    const float* c2 = CTXp + b*HID;
    #pragma unroll
    for (int pass=0; pass<3; ++pass){
      int o = pass*32 + (tid>>3);
      if (o<TGT){
        int j = tid&7;
        const float* pw = projw + (size_t)o*1024;
        float a=0.f;
        for (int i=0;i<16;i++){
          int k = j*128 + i*8;
          const float* zp = (k<512)? dh+k : c2+(k-512);
          float z[8]; ld8f(zp,z);
          float wv[8]; ld8f(pw+k,wv);
          a += dot8(wv,z);
        }
        a += __shfl_xor(a,1); a += __shfl_xor(a,2); a += __shfl_xor(a,4);
        if (j==0) MEL[((size_t)b*TD + (t-1))*TGT + o] = a;
      }
    }
    return;
  }
  int b = blk>>2, k4 = blk&3;
  __shared__ float qs[128], vv[128];
  __shared__ __align__(16) float el[608], wl[608];
  __shared__ float part[256];
  __shared__ float red[4];
  // q-projection (redundant per k4; qw is L2-hot)
  if (tid < 128){
    vv[tid] = vw[tid];
    const float* qr = qw + (size_t)tid*HID;
    const float* ah = AH + b*HID;
    float acc = 0.f;
    for (int kk=0;kk<HID;kk+=8){
      float wv2[8]; ld8f(qr+kk,wv2);
      acc += dot8(wv2, ah+kk);
    }
    qs[tid] = acc;
  }
  __syncthreads();
  // thread-parallel E assembly: each thread owns t' rows (full 128-dot each)
  for (int r=0;r<3;r++){
    int tt=tid+r*256;
    if (tt<TE){
      const uint4* pm4=(const uint4*)(PM +((size_t)b*TE+tt)*ATTD);
      const uint4* lc4=(const uint4*)(LOC+((size_t)b*TE+tt)*ATTD);
      float s=0.f;
      #pragma unroll 4
      for (int g=0;g<16;g++){
        uint4 um=pm4[g], ul=lc4[g];
        unsigned mm[4]={um.x,um.y,um.z,um.w};
        unsigned ll[4]={ul.x,ul.y,ul.z,ul.w};
        #pragma unroll
        for (int q=0;q<4;q++){
          int a=g*8+q*2;
          float x0=qs[a]  +__uint_as_float(mm[q]<<16)
                          +__uint_as_float(ll[q]<<16);
          float x1=qs[a+1]+__uint_as_float(mm[q]&0xFFFF0000u)
                          +__uint_as_float(ll[q]&0xFFFF0000u);
          s+=vv[a]*tanhfast(x0)+vv[a+1]*tanhfast(x1);
        }
      }
      el[tt]=s;
    }
  }
  __syncthreads();
  // softmax over el[0..599]
  float e0[3]; float mx=-1e30f;
  #pragma unroll
  for (int r=0;r<3;r++){
    int i=tid+r*256;
    float v=(i<TE)? el[i] : -1e30f;
    e0[r]=v; mx=fmaxf(mx,v);
  }
  for (int off=1;off<64;off<<=1) mx=fmaxf(mx,__shfl_xor(mx,off));
  if ((tid&63)==0) red[tid>>6]=mx;
  __syncthreads();
  float m=fmaxf(fmaxf(red[0],red[1]),fmaxf(red[2],red[3]));
  float ex[3]; float s=0.f;
  #pragma unroll
  for (int r=0;r<3;r++){
    int i=tid+r*256;
    ex[r]=(i<TE)? __expf(e0[r]-m) : 0.f;
    s+=ex[r];
  }
  for (int off=1;off<64;off<<=1) s+=__shfl_xor(s,off);
  __syncthreads();
  if ((tid&63)==0) red[tid>>6]=s;
  __syncthreads();
  float inv=1.f/(red[0]+red[1]+red[2]+red[3]);
  #pragma unroll
  for (int r=0;r<3;r++){
    int i=tid+r*256;
    if (i<TE){
      float w2=ex[r]*inv;
      wl[i]=w2;
      if (k4==0){
        W[(size_t)b*TE+i]=w2;
        WCUM[(size_t)b*TE+i]+=w2;
      }
    }
  }
  __syncthreads();
  // ctx slice: h in [k4*128, k4*128+128)
  {
    int hl = tid&127, tl = tid>>7;
    int h = k4*128 + hl;
    const float* ep = enc + ((size_t)b*TE)*HID + h;
    float a0=0.f,a1=0.f,a2=0.f;
    for (int u=0; u<100; ++u){
      int tt = tl + u*6;
      a0 += wl[tt  ]*ep[(size_t)(tt  )*HID];
      a1 += wl[tt+2]*ep[(size_t)(tt+2)*HID];
      a2 += wl[tt+4]*ep[(size_t)(tt+4)*HID];
    }
    part[tid]=a0+a1+a2;
  }
  __syncthreads();
  if (tid<128)
    CTXw[b*HID + k4*128 + tid] = part[tid] + part[128+tid];
}

// ---------------- phase EA: lstmA(t+1) || lstmD(t) || conv+fc -> LOC(t+1) --
// blocks [0,512): lstmA(t+1), cell=blk; [512,1024): lstmD(t), cell=blk-512;
// [1024,1280): conv+fc, idx=blk-1024: b=idx>>3, s8=idx&7 (75 t' each)
// WBF=1: LSTM weights are bf16 (pre-converted); WBF=0: original fp32 weights.
template<int WBF>
__global__ __launch_bounds__(256) void k_ea(
    const bf16* __restrict__ XS,
    const float* __restrict__ CTXt, const float* __restrict__ AHt,
    float* __restrict__ AHw, float* __restrict__ AC,
    const float* __restrict__ DHp, float* __restrict__ DHw, float* __restrict__ DC,
    const float* __restrict__ W, const float* __restrict__ WCUM,
    const float* __restrict__ convw, const float* __restrict__ fcw,
    bf16* __restrict__ LOC,
    const void* __restrict__ awih_, const void* __restrict__ awhh_,
    const float* __restrict__ abih, const float* __restrict__ abhh,
    const void* __restrict__ dwih_, const void* __restrict__ dwhh_,
    const float* __restrict__ dbih, const float* __restrict__ dbhh,
    int t)
{
  int blk=blockIdx.x, tid=threadIdx.x;
  if (blk<512){
    int s = t+1;
    if (s>=TD) return;
    int b=tid>>3, j=tid&7;
    int cell = blk;
    const bf16* xs = XS + ((size_t)s*NB+b)*PREN;
    const float* cx = CTXt + b*HID;
    const float* hr = AHt + b*HID;
    float acc[4];
    #pragma unroll
    for (int q=0;q<4;q++) acc[q]=0.f;
    for (int i=0;i<20;i++){
      int k8=i*64+j*8;
      float z[8];
      if (k8<256) ld8bf(xs+k8,z);
      else ld8f((k8<768)? cx+(k8-256) : hr+(k8-768), z);
      #pragma unroll
      for (int g=0;g<4;g++){
        int row = g*HID + cell;
        float wv[8];
        if (WBF){
          const bf16* wp = (k8<768) ? ((const bf16*)awih_ + (size_t)row*768 + k8)
                                    : ((const bf16*)awhh_ + (size_t)row*HID + (k8-768));
          ld8bf(wp,wv);
        } else {
          const float* wp = (k8<768) ? ((const float*)awih_ + (size_t)row*768 + k8)
                                     : ((const float*)awhh_ + (size_t)row*HID + (k8-768));
          ld8f(wp,wv);
        }
        acc[g] += dot8(wv,z);
      }
    }
    #pragma unroll
    for (int q=0;q<4;q++){
      acc[q] += __shfl_xor(acc[q],1);
      acc[q] += __shfl_xor(acc[q],2);
      acc[q] += __shfl_xor(acc[q],4);
    }
    if (j==0){
      float g0=acc[0]+abih[0*HID+cell]+abhh[0*HID+cell];
      float g1=acc[1]+abih[1*HID+cell]+abhh[1*HID+cell];
      float g2=acc[2]+abih[2*HID+cell]+abhh[2*HID+cell];
      float g3=acc[3]+abih[3*HID+cell]+abhh[3*HID+cell];
      float c2 = sigm(g1)*AC[b*HID+cell] + sigm(g0)*tanhfast(g2);
      AC[b*HID+cell]=c2;
      AHw[b*HID+cell]=sigm(g3)*tanhfast(c2);
    }
  } else if (blk<1024){
    if (t<0) return;
    int b=tid>>3, j=tid&7;
    int cell = blk-512;
    const float* ah  = AHt + b*HID;
    const float* cx  = CTXt + b*HID;
    const float* dhr = DHp + b*HID;
    float acc[4];
    #pragma unroll
    for (int q=0;q<4;q++) acc[q]=0.f;
    for (int i=0;i<24;i++){
      int k8=i*64+j*8;
      const float* zp = (k8<512)? ah+k8 : (k8<1024)? cx+(k8-512) : dhr+(k8-1024);
      float z[8]; ld8f(zp,z);
      #pragma unroll
      for (int g=0;g<4;g++){
        int row = g*HID + cell;
        float wv[8];
        if (WBF){
          const bf16* wp = (k8<1024) ? ((const bf16*)dwih_ + (size_t)row*1024 + k8)
                                     : ((const bf16*)dwhh_ + (size_t)row*HID + (k8-1024));
          ld8bf(wp,wv);
        } else {
          const float* wp = (k8<1024) ? ((const float*)dwih_ + (size_t)row*1024 + k8)
                                      : ((const float*)dwhh_ + (size_t)row*HID + (k8-1024));
          ld8f(wp,wv);
        }
        acc[g] += dot8(wv,z);
      }
    }
    #pragma unroll
    for (int q=0;q<4;q++){
      acc[q] += __shfl_xor(acc[q],1);
      acc[q] += __shfl_xor(acc[q],2);
      acc[q] += __shfl_xor(acc[q],4);
    }
    if (j==0){
      float g0=acc[0]+dbih[0*HID+cell]+dbhh[0*HID+cell];
      float g1=acc[1]+dbih[1*HID+cell]+dbhh[1*HID+cell];
      float g2=acc[2]+dbih[2*HID+cell]+dbhh[2*HID+cell];
      float g3=acc[3]+dbih[3*HID+cell]+dbhh[3*HID+cell];
      float c2 = sigm(g1)*DC[b*HID+cell] + sigm(g0)*tanhfast(g2);
      DC[b*HID+cell]=c2;
      DHw[b*HID+cell]=sigm(g3)*tanhfast(c2);
    }
  } else {
    // conv + fc -> LOC for step t+1 (uses W(t), WCUM(t))
    if (t+1>=TD) return;
    int idx = blk-1024;
    int b = idx>>3, s8 = idx&7;
    int tb = s8*75;
    __shared__ __align__(16) float wp_[112], wc_[112];
    __shared__ __align__(16) float cw0[32*31], cw1[32*31];
    __shared__ __align__(16) float cb[75*32];
    __shared__ __align__(16) float fcs[128*33];
    if (tid<105){
      int g = tb-15+tid;
      bool ok = (g>=0 && g<TE);
      wp_[tid] = ok ? W[(size_t)b*TE+g] : 0.f;
      wc_[tid] = ok ? WCUM[(size_t)b*TE+g] : 0.f;
    }
    for (int i=tid;i<32*31;i+=256){
      int c=i/31, k=i-c*31;
      cw0[i] = convw[c*62 + k];
      cw1[i] = convw[c*62 + 31 + k];
    }
    for (int i=tid;i<128*33;i+=256){
      int a=i/33, c=i-a*33;
      fcs[i] = (c<32)? fcw[a*32+c] : 0.f;
    }
    __syncthreads();
    for (int i=tid;i<75*32;i+=256){
      int tt=i>>5, c=i&31;
      float s=0.f;
      for (int k=0;k<LK;k++)
        s += cw0[c*31+k]*wp_[tt+k] + cw1[c*31+k]*wc_[tt+k];
      cb[tt*32+c]=s;
    }
    __syncthreads();
    {
      int lane = tid&63, tl = tid>>6;
      int a0 = 2*lane;
      for (int tt=tl; tt<75; tt+=4){
        float l0=0.f, l1=0.f;
        const float* cbr = cb + tt*32;
        #pragma unroll
        for (int c=0;c<32;c++){
          float cv = cbr[c];
          l0 += fcs[a0*33+c]*cv;
          l1 += fcs[(a0+1)*33+c]*cv;
        }
        size_t off = ((size_t)b*TE + tb + tt)*ATTD + a0;
        LOC[off]   = __float2bfloat16(l0);
        LOC[off+1] = __float2bfloat16(l1);
      }
    }
  }
}

// ---------------- final-step mel -----------------
__global__ __launch_bounds__(256) void k_melfinal(const float* __restrict__ DH,
    const float* __restrict__ CTX, const float* __restrict__ projw, float* __restrict__ MEL)
{
  int gid=blockIdx.x*256+threadIdx.x;
  if (gid>=NB*TGT) return;
  int o=gid%TGT, b=gid/TGT;
  const float* pw=projw+(size_t)o*1024;
  float a=0.f;
  for (int k=0;k<HID;k+=8){
    float wv[8]; ld8f(pw+k,wv);
    a += dot8(wv, DH + b*HID + k);
  }
  for (int k=0;k<HID;k+=8){
    float wv[8]; ld8f(pw+512+k,wv);
    a += dot8(wv, CTX + b*HID + k);
  }
  MEL[((size_t)b*TD+599)*TGT+o]=a;
}

// ---------------- postnet conv (generic, bf16 internal activations) --------
__global__ __launch_bounds__(256) void k_conv(
    const void* __restrict__ inv_, bf16* __restrict__ out,
    const float* __restrict__ w, const float* __restrict__ bias,
    int IC, int OC, int mel_in, int do_tanh, int b0)
{
  __shared__ __align__(16) float xs[256*36];
  int bl=blockIdx.x, bg=b0+bl, oct=blockIdx.y, t0=blockIdx.z*32, tid=threadIdx.x;
  int oc = oct*256 + tid;
  float acc[32];
  #pragma unroll
  for (int q=0;q<32;q++) acc[q]=0.f;
  int nch=(IC+255)/256;
  const float* inf_ = (const float*)inv_;
  const bf16*  inb_ = (const bf16*)inv_;
  for (int ch=0;ch<nch;ch++){
    int icb=ch*256, icn=min(256,IC-icb);
    __syncthreads();
    for (int i=tid;i<icn*36;i+=256){
      int icl=i/36, tt=i-icl*36;
      int tg=t0+tt-2;
      float v=0.f;
      if (tg>=0 && tg<TD){
        int ic=icb+icl;
        v = mel_in ? inf_[((size_t)bg*TD+tg)*TGT+ic]
                   : b2f(inb_[((size_t)bl*IC+ic)*TD+tg]);
      }
      xs[i]=v;
    }
    __syncthreads();
    if (oc<OC){
      const float* wp = w + ((size_t)oc*IC+icb)*5;
      for (int ic=0;ic<icn;ic++){
        float xw[36];
        #pragma unroll
        for (int q=0;q<9;q++) ((float4*)xw)[q]=((const float4*)(xs+ic*36))[q];
        float wk0=wp[ic*5  ],wk1=wp[ic*5+1],wk2=wp[ic*5+2],
              wk3=wp[ic*5+3],wk4=wp[ic*5+4];
        #pragma unroll
        for (int tt=0;tt<32;tt++)
          acc[tt] += wk0*xw[tt]+wk1*xw[tt+1]+wk2*xw[tt+2]+wk3*xw[tt+3]+wk4*xw[tt+4];
      }
    }
  }
  if (oc<OC){
    float bv=bias[oc];
    for (int tt=0;tt<32;tt++){
      int tg=t0+tt;
      if (tg<TD){
        float v=acc[tt]+bv;
        if (do_tanh) v=tanhfast(v);
        out[((size_t)bl*OC+oc)*TD+tg]=__float2bfloat16(v);
      }
    }
  }
}

// ---------------- postnet last layer + in-place residual on d_out ----------
__global__ __launch_bounds__(256) void k_conv_last(
    const bf16* __restrict__ in, const float* __restrict__ w,
    const float* __restrict__ bias, float* __restrict__ outp, int b0)
{
  __shared__ __align__(16) float xs[256*36];
  int bl=blockIdx.x, bg=b0+bl, t0=blockIdx.z*32, tid=threadIdx.x;
  int oc = tid;
  float acc[32];
  #pragma unroll
  for (int q=0;q<32;q++) acc[q]=0.f;
  for (int ch=0;ch<2;ch++){
    int icb=ch*256;
    __syncthreads();
    for (int i=tid;i<256*36;i+=256){
      int icl=i/36, tt=i-icl*36;
      int tg=t0+tt-2;
      float v=0.f;
      if (tg>=0 && tg<TD){
        int ic=icb+icl;
        v = b2f(in[((size_t)bl*PH+ic)*TD+tg]);
      }
      xs[i]=v;
    }
    __syncthreads();
    if (oc<TGT){
      const float* wp = w + ((size_t)oc*PH+icb)*5;
      for (int ic=0;ic<256;ic++){
        float xw[36];
        #pragma unroll
        for (int q=0;q<9;q++) ((float4*)xw)[q]=((const float4*)(xs+ic*36))[q];
        float wk0=wp[ic*5  ],wk1=wp[ic*5+1],wk2=wp[ic*5+2],
              wk3=wp[ic*5+3],wk4=wp[ic*5+4];
        #pragma unroll
        for (int tt=0;tt<32;tt++)
          acc[tt] += wk0*xw[tt]+wk1*xw[tt+1]+wk2*xw[tt+2]+wk3*xw[tt+3]+wk4*xw[tt+4];
      }
    }
  }
  if (oc<TGT){
    float bv=bias[oc];
    for (int tt=0;tt<32;tt++){
      int tg=t0+tt;
      if (tg<TD){
        size_t idx=((size_t)bg*TD+tg)*TGT+oc;
        outp[idx]=acc[tt]+bv+outp[idx];
      }
    }
  }
}

extern "C" void kernel_launch(void* const* d_in, const int* in_sizes, int n_in,
                              void* d_out, int out_size, void* d_ws, size_t ws_size,
                              hipStream_t stream)
{
  const float* enc =(const float*)d_in[0];
  const float* dec =(const float*)d_in[1];
  const float* pw1 =(const float*)d_in[2];  const float* pb1=(const float*)d_in[3];
  const float* pw2 =(const float*)d_in[4];  const float* pb2=(const float*)d_in[5];
  const float* awih=(const float*)d_in[6];  const float* awhh=(const float*)d_in[7];
  const float* abih=(const float*)d_in[8];  const float* abhh=(const float*)d_in[9];
  const float* dwih=(const float*)d_in[10]; const float* dwhh=(const float*)d_in[11];
  const float* dbih=(const float*)d_in[12]; const float* dbhh=(const float*)d_in[13];
  const float* memw=(const float*)d_in[14]; const float* memb=(const float*)d_in[15];
  const float* qw  =(const float*)d_in[16];
  const float* lcw =(const float*)d_in[17];
  const float* lfw =(const float*)d_in[18];
  const float* vw  =(const float*)d_in[19];
  const float* pjw =(const float*)d_in[20];
  const float* cwt0=(const float*)d_in[21]; const float* cbt0=(const float*)d_in[22];
  const float* cwt1=(const float*)d_in[23]; const float* cbt1=(const float*)d_in[24];
  const float* cwt2=(const float*)d_in[25]; const float* cbt2=(const float*)d_in[26];
  const float* cwt3=(const float*)d_in[27]; const float* cbt3=(const float*)d_in[28];
  const float* cwt4=(const float*)d_in[29]; const float* cbt4=(const float*)d_in[30];
  float* MEL = (float*)d_out;
  (void)in_sizes; (void)n_in; (void)out_size;

  // ---- workspace layout (~20.34 MB base; +11.53 MB optional bf16 weights) ----
  char* base=(char*)d_ws;
  const size_t XS_B = (size_t)TD*NB*PREN*2;   //  9,830,400 B
  const size_t PM_B = (size_t)NB*TE*ATTD*2;   //  4,915,200 B
  const size_t HB   = (size_t)NB*HID*4;       //     65,536 B
  const size_t WB   = (size_t)NB*TE*4;        //     76,800 B
  const size_t LOC_B= (size_t)NB*TE*ATTD*2;   //  4,915,200 B
  bf16* XSb = (bf16*)base;
  bf16* PMb = (bf16*)(base + XS_B);
  char* sbase = base + XS_B + PM_B;
  float* AHb[2], *DHb[2], *CTXb[2];
  AHb[0] =(float*)(sbase+0*HB);
  AHb[1] =(float*)(sbase+1*HB);
  float* ACb =(float*)(sbase+2*HB);
  DHb[0] =(float*)(sbase+3*HB);
  DHb[1] =(float*)(sbase+4*HB);
  float* DCb =(float*)(sbase+5*HB);
  CTXb[0]=(float*)(sbase+6*HB);
  CTXb[1]=(float*)(sbase+7*HB);
  float* Wb  =(float*)(sbase+8*HB);
  float* WC  =(float*)(sbase+8*HB+WB);
  bf16*  LOCb=(bf16*)(sbase+8*HB+2*WB);

  // optional bf16 LSTM weights after LOC
  const size_t BASE_B = XS_B + PM_B + 8*HB + 2*WB + LOC_B;   // 20,338,688
  bf16* AWIHb=(bf16*)(base + BASE_B);
  bf16* AWHHb=AWIHb + (size_t)2048*768;
  bf16* DWIHb=AWHHb + (size_t)2048*512;
  bf16* DWHHb=DWIHb + (size_t)2048*1024;
  const size_t WBF_B = ((size_t)2048*768 + 2048*512 + 2048*1024 + 2048*512)*2;
  const bool useb = (ws_size >= BASE_B + WBF_B);

  const int G = 8;
  const size_t PBc_B = (size_t)G*PH*TD*2;
  bf16* PB0 = (bf16*)base;
  bf16* PB1 = (bf16*)(base + PBc_B);

  hipMemsetAsync(sbase, 0, 8*HB+2*WB, stream);

  if (useb){
    k_w2b<<<512,256,0,stream>>>(awih,AWIHb,2048*768);
    k_w2b<<<512,256,0,stream>>>(awhh,AWHHb,2048*512);
    k_w2b<<<512,256,0,stream>>>(dwih,DWIHb,2048*1024);
    k_w2b<<<512,256,0,stream>>>(dwhh,DWHHb,2048*512);
  }
  k_prenet<<<TD,256,0,stream>>>(dec,pw1,pb1,pw2,pb2,XSb);
  k_procmem<<<TE,256,0,stream>>>(enc,memw,memb,PMb);

  // prologue: lstmA(0) + LOC(0) (from zero W/WCUM -> zeros)
  if (useb){
    k_ea<1><<<1280,256,0,stream>>>(XSb, CTXb[1], AHb[1], AHb[0], ACb,
                                   DHb[0], DHb[1], DCb, Wb, WC, lcw, lfw, LOCb,
                                   AWIHb,AWHHb,abih,abhh,DWIHb,DWHHb,dbih,dbhh, -1);
  } else {
    k_ea<0><<<1280,256,0,stream>>>(XSb, CTXb[1], AHb[1], AHb[0], ACb,
                                   DHb[0], DHb[1], DCb, Wb, WC, lcw, lfw, LOCb,
                                   awih,awhh,abih,abhh,dwih,dwhh,dbih,dbhh, -1);
  }
  for (int t=0;t<TD;t++){
    float* AHt  = AHb[t&1];        // AH(t)
    float* AHw  = AHb[(t+1)&1];    // AH(t+1)
    float* DHp  = DHb[(t+1)&1];    // DH(t-1)
    float* DHw  = DHb[t&1];        // DH(t)
    float* CTXt = CTXb[t&1];       // CTX(t)
    float* CTXp = CTXb[(t+1)&1];   // CTX(t-1)
    k_bc<<<160,256,0,stream>>>(AHt, PMb, LOCb, enc, qw, vw,
                               Wb, WC, CTXt, DHp, CTXp, pjw, MEL, t);
    if (useb){
      k_ea<1><<<1280,256,0,stream>>>(XSb, CTXt, AHt, AHw, ACb,
                                     DHp, DHw, DCb, Wb, WC, lcw, lfw, LOCb,
                                     AWIHb,AWHHb,abih,abhh,DWIHb,DWHHb,dbih,dbhh, t);
    } else {
      k_ea<0><<<1280,256,0,stream>>>(XSb, CTXt, AHt, AHw, ACb,
                                     DHp, DHw, DCb, Wb, WC, lcw, lfw, LOCb,
                                     awih,awhh,abih,abhh,dwih,dwhh,dbih,dbhh, t);
    }
  }
  // DH(599)=DHb[1], CTX(599)=CTXb[1]
  k_melfinal<<<10,256,0,stream>>>(DHb[1],CTXb[1],pjw,MEL);

  // postnet in 4 batch-chunks of G=8 (buffers fit the dead XS region)
  for (int c=0;c<NB/G;c++){
    int b0=c*G;
    k_conv<<<dim3(G,2,19),256,0,stream>>>(MEL,PB0,cwt0,cbt0,TGT,PH,1,1,b0);
    k_conv<<<dim3(G,2,19),256,0,stream>>>(PB0,PB1,cwt1,cbt1,PH,PH,0,1,b0);
    k_conv<<<dim3(G,2,19),256,0,stream>>>(PB1,PB0,cwt2,cbt2,PH,PH,0,1,b0);
    k_conv<<<dim3(G,2,19),256,0,stream>>>(PB0,PB1,cwt3,cbt3,PH,PH,0,1,b0);
    k_conv_last<<<dim3(G,1,19),256,0,stream>>>(PB1,cwt4,cbt4,MEL,b0);
  }
}

// Round 10
// 59207.532 us; speedup vs baseline: 1.0684x; 1.0684x over previous
//
#include <hip/hip_runtime.h>
#include <hip/hip_bf16.h>

typedef __hip_bfloat16 bf16;

#define NB   32
#define TE   600
#define TD   600
#define TGT  80
#define PREN 256
#define HID  512
#define ATTD 128
#define LF   32
#define LK   31
#define PH   512

__device__ __forceinline__ float b2f(bf16 x){ return __bfloat162float(x); }

__device__ __forceinline__ void ld8bf(const bf16* p, float* o){
  const uint4 u = *(const uint4*)p;
  o[0]=__uint_as_float(u.x<<16); o[1]=__uint_as_float(u.x&0xFFFF0000u);
  o[2]=__uint_as_float(u.y<<16); o[3]=__uint_as_float(u.y&0xFFFF0000u);
  o[4]=__uint_as_float(u.z<<16); o[5]=__uint_as_float(u.z&0xFFFF0000u);
  o[6]=__uint_as_float(u.w<<16); o[7]=__uint_as_float(u.w&0xFFFF0000u);
}

__device__ __forceinline__ void ld8f(const float* p, float* o){
  float4 a=*(const float4*)p, b=*(const float4*)(p+4);
  o[0]=a.x;o[1]=a.y;o[2]=a.z;o[3]=a.w;
  o[4]=b.x;o[5]=b.y;o[6]=b.z;o[7]=b.w;
}

__device__ __forceinline__ float dot8(const float* w, const float* z){
  return w[0]*z[0]+w[1]*z[1]+w[2]*z[2]+w[3]*z[3]
       + w[4]*z[4]+w[5]*z[5]+w[6]*z[6]+w[7]*z[7];
}

__device__ __forceinline__ float sigm(float x){ return 1.f/(1.f+__expf(-x)); }
__device__ __forceinline__ float tanhfast(float x){
  float e = __expf(2.f*x);
  return 1.f - 2.f/(e+1.f);
}

// ---------------- prenet: XS[t][b][256] (bf16) -----------------
__global__ __launch_bounds__(256) void k_prenet(const float* __restrict__ dec,
    const float* __restrict__ w1, const float* __restrict__ b1,
    const float* __restrict__ w2, const float* __restrict__ b2,
    bf16* __restrict__ XS)
{
  int t = blockIdx.x, tid = threadIdx.x;
  __shared__ __align__(16) float fr[NB*TGT];
  __shared__ __align__(16) float h1[NB*PREN];
  for (int i=tid;i<NB*TGT;i+=256){
    int b=i/TGT,c=i%TGT;
    fr[b*TGT+c] = (t==0)?0.f:dec[((size_t)b*TD+(t-1))*TGT+c];
  }
  __syncthreads();
  {
    int oc=tid; float bb=b1[oc];
    const float* wr = w1 + (size_t)oc*TGT;
    for (int b=0;b<NB;b++){
      float acc=bb;
      for (int k=0;k<TGT;k+=8){
        float wv[8]; ld8f(wr+k,wv);
        acc += dot8(wv, fr + b*TGT + k);
      }
      h1[b*PREN+oc]=fmaxf(acc,0.f);
    }
  }
  __syncthreads();
  {
    int oc=tid; float bb=b2[oc];
    const float* wr = w2 + (size_t)oc*PREN;
    for (int b=0;b<NB;b++){
      float acc=bb;
      for (int k=0;k<PREN;k+=8){
        float wv[8]; ld8f(wr+k,wv);
        acc += dot8(wv, h1 + b*PREN + k);
      }
      XS[((size_t)t*NB+b)*PREN+oc]=__float2bfloat16(fmaxf(acc,0.f));
    }
  }
}

// ---------------- proc_mem: PM[b][t][128] (bf16) -----------------
__global__ __launch_bounds__(256) void k_procmem(const float* __restrict__ enc,
    const float* __restrict__ mw, const float* __restrict__ mb, bf16* __restrict__ PM)
{
  int t=blockIdx.x, tid=threadIdx.x;
  __shared__ __align__(16) float xe[16*HID];
  int a = tid & 127, bh = tid >> 7;
  float bb = mb[a];
  const float* wr = mw + (size_t)a*HID;
  for (int half=0; half<2; half++){
    __syncthreads();
    for (int i=tid;i<16*HID;i+=256){
      int bl=i>>9, h=i&511;
      xe[i] = enc[((size_t)(half*16+bl)*TE + t)*HID + h];
    }
    __syncthreads();
    for (int bl=bh*8; bl<bh*8+8; bl++){
      float acc=bb;
      for (int k=0;k<HID;k+=8){
        float wv[8]; ld8f(wr+k,wv);
        acc += dot8(wv, xe + bl*HID + k);
      }
      PM[((size_t)(half*16+bl)*TE + t)*ATTD + a] = __float2bfloat16(acc);
    }
  }
}

// ---------------- phase BC: E-assembly + softmax + ctx + mel(t-1) ---------
// grid 160: blk<128: (b=blk>>2, k4=blk&3) E+softmax+ctx-slice
//           blk in [128,160): mel block, b = blk-128
// PML[b][t'][a] = PM + LOC pre-summed (bf16), produced by k_ea each step.
__global__ __launch_bounds__(256) void k_bc(
    const float* __restrict__ AH, const bf16* __restrict__ PML,
    const float* __restrict__ enc,
    const float* __restrict__ qw, const float* __restrict__ vw,
    float* __restrict__ W, float* __restrict__ WCUM, float* __restrict__ CTXw,
    const float* __restrict__ DHp, const float* __restrict__ CTXp,
    const float* __restrict__ projw, float* __restrict__ MEL, int t)
{
  int blk=blockIdx.x, tid=threadIdx.x;
  if (blk>=128){
    // ---- mel(t-1): reads DH(t-1), CTX(t-1) (both stable this phase) ----
    if (t==0) return;
    int b = blk-128;
    const float* dh = DHp + b*HID;
    const float* c2 = CTXp + b*HID;
    #pragma unroll
    for (int pass=0; pass<3; ++pass){
      int o = pass*32 + (tid>>3);
      if (o<TGT){
        int j = tid&7;
        const float* pw = projw + (size_t)o*1024;
        float a=0.f;
        for (int i=0;i<16;i++){
          int k = j*128 + i*8;
          const float* zp = (k<512)? dh+k : c2+(k-512);
          float z[8]; ld8f(zp,z);
          float wv[8]; ld8f(pw+k,wv);
          a += dot8(wv,z);
        }
        a += __shfl_xor(a,1); a += __shfl_xor(a,2); a += __shfl_xor(a,4);
        if (j==0) MEL[((size_t)b*TD + (t-1))*TGT + o] = a;
      }
    }
    return;
  }
  int b = blk>>2, k4 = blk&3;
  __shared__ float qs[128], vv[128];
  __shared__ __align__(16) float el[608], wl[608];
  __shared__ __align__(16) float4 part4[256];
  __shared__ float red[4];
  // q-projection (redundant per k4; qw is L2-hot)
  if (tid < 128){
    vv[tid] = vw[tid];
    const float* qr = qw + (size_t)tid*HID;
    const float* ah = AH + b*HID;
    float acc = 0.f;
    for (int kk=0;kk<HID;kk+=8){
      float wv2[8]; ld8f(qr+kk,wv2);
      acc += dot8(wv2, ah+kk);
    }
    qs[tid] = acc;
  }
  __syncthreads();
  // thread-parallel E assembly: each thread owns t' rows (full 128-dot each)
  for (int r=0;r<3;r++){
    int tt=tid+r*256;
    if (tt<TE){
      const uint4* pm4=(const uint4*)(PML+((size_t)b*TE+tt)*ATTD);
      float s=0.f;
      #pragma unroll 4
      for (int g=0;g<16;g++){
        uint4 um=pm4[g];
        unsigned mm[4]={um.x,um.y,um.z,um.w};
        #pragma unroll
        for (int q=0;q<4;q++){
          int a=g*8+q*2;
          float x0=qs[a]  +__uint_as_float(mm[q]<<16);
          float x1=qs[a+1]+__uint_as_float(mm[q]&0xFFFF0000u);
          s+=vv[a]*tanhfast(x0)+vv[a+1]*tanhfast(x1);
        }
      }
      el[tt]=s;
    }
  }
  __syncthreads();
  // softmax over el[0..599]
  float e0[3]; float mx=-1e30f;
  #pragma unroll
  for (int r=0;r<3;r++){
    int i=tid+r*256;
    float v=(i<TE)? el[i] : -1e30f;
    e0[r]=v; mx=fmaxf(mx,v);
  }
  for (int off=1;off<64;off<<=1) mx=fmaxf(mx,__shfl_xor(mx,off));
  if ((tid&63)==0) red[tid>>6]=mx;
  __syncthreads();
  float m=fmaxf(fmaxf(red[0],red[1]),fmaxf(red[2],red[3]));
  float ex[3]; float s=0.f;
  #pragma unroll
  for (int r=0;r<3;r++){
    int i=tid+r*256;
    ex[r]=(i<TE)? __expf(e0[r]-m) : 0.f;
    s+=ex[r];
  }
  for (int off=1;off<64;off<<=1) s+=__shfl_xor(s,off);
  __syncthreads();
  if ((tid&63)==0) red[tid>>6]=s;
  __syncthreads();
  float inv=1.f/(red[0]+red[1]+red[2]+red[3]);
  #pragma unroll
  for (int r=0;r<3;r++){
    int i=tid+r*256;
    if (i<TE){
      float w2=ex[r]*inv;
      wl[i]=w2;
      if (k4==0){
        W[(size_t)b*TE+i]=w2;
        WCUM[(size_t)b*TE+i]+=w2;
      }
    }
  }
  __syncthreads();
  // ctx slice: h in [k4*128, k4*128+128), float4 per thread
  {
    int hl = tid&31, tl = tid>>5;           // 32 h-groups x 8 t-lanes
    int h = k4*128 + hl*4;
    const float4* ep4 = (const float4*)(enc + ((size_t)b*TE)*HID + h);
    float4 acc; acc.x=0.f; acc.y=0.f; acc.z=0.f; acc.w=0.f;
    for (int u=0; u<75; ++u){
      int tt = tl + u*8;
      float w = wl[tt];
      float4 e = ep4[(size_t)tt*(HID/4)];
      acc.x += w*e.x; acc.y += w*e.y; acc.z += w*e.z; acc.w += w*e.w;
    }
    part4[tid]=acc;
  }
  __syncthreads();
  if (tid<32){
    float4 s4; s4.x=0.f; s4.y=0.f; s4.z=0.f; s4.w=0.f;
    #pragma unroll
    for (int k=0;k<8;k++){
      float4 p = part4[k*32+tid];
      s4.x+=p.x; s4.y+=p.y; s4.z+=p.z; s4.w+=p.w;
    }
    *(float4*)(CTXw + b*HID + k4*128 + tid*4) = s4;
  }
}

// ---------------- phase EA: lstmA(t+1) || lstmD(t) || conv+fc -> PML(t+1) --
// blocks [0,512): lstmA(t+1), cell=blk; [512,1024): lstmD(t), cell=blk-512;
// [1024,1280): conv+fc, idx=blk-1024: b=idx>>3, s8=idx&7 (75 t' each)
__global__ __launch_bounds__(256) void k_ea(
    const bf16* __restrict__ XS,
    const float* __restrict__ CTXt, const float* __restrict__ AHt,
    float* __restrict__ AHw, float* __restrict__ AC,
    const float* __restrict__ DHp, float* __restrict__ DHw, float* __restrict__ DC,
    const float* __restrict__ W, const float* __restrict__ WCUM,
    const float* __restrict__ convw, const float* __restrict__ fcw,
    const bf16* __restrict__ PM, bf16* __restrict__ PML,
    const float* __restrict__ awih, const float* __restrict__ awhh,
    const float* __restrict__ abih, const float* __restrict__ abhh,
    const float* __restrict__ dwih, const float* __restrict__ dwhh,
    const float* __restrict__ dbih, const float* __restrict__ dbhh,
    int t)
{
  int blk=blockIdx.x, tid=threadIdx.x;
  if (blk<512){
    int s = t+1;
    if (s>=TD) return;
    int b=tid>>3, j=tid&7;
    int cell = blk;
    const bf16* xs = XS + ((size_t)s*NB+b)*PREN;
    const float* cx = CTXt + b*HID;
    const float* hr = AHt + b*HID;
    float acc[4];
    #pragma unroll
    for (int q=0;q<4;q++) acc[q]=0.f;
    for (int i=0;i<20;i++){
      int k8=i*64+j*8;
      float z[8];
      if (k8<256) ld8bf(xs+k8,z);
      else ld8f((k8<768)? cx+(k8-256) : hr+(k8-768), z);
      #pragma unroll
      for (int g=0;g<4;g++){
        int row = g*HID + cell;
        const float* wp = (k8<768) ? (awih + (size_t)row*768 + k8)
                                   : (awhh + (size_t)row*HID + (k8-768));
        float wv[8]; ld8f(wp,wv);
        acc[g] += dot8(wv,z);
      }
    }
    #pragma unroll
    for (int q=0;q<4;q++){
      acc[q] += __shfl_xor(acc[q],1);
      acc[q] += __shfl_xor(acc[q],2);
      acc[q] += __shfl_xor(acc[q],4);
    }
    if (j==0){
      float g0=acc[0]+abih[0*HID+cell]+abhh[0*HID+cell];
      float g1=acc[1]+abih[1*HID+cell]+abhh[1*HID+cell];
      float g2=acc[2]+abih[2*HID+cell]+abhh[2*HID+cell];
      float g3=acc[3]+abih[3*HID+cell]+abhh[3*HID+cell];
      float c2 = sigm(g1)*AC[b*HID+cell] + sigm(g0)*tanhfast(g2);
      AC[b*HID+cell]=c2;
      AHw[b*HID+cell]=sigm(g3)*tanhfast(c2);
    }
  } else if (blk<1024){
    if (t<0) return;
    int b=tid>>3, j=tid&7;
    int cell = blk-512;
    const float* ah  = AHt + b*HID;
    const float* cx  = CTXt + b*HID;
    const float* dhr = DHp + b*HID;
    float acc[4];
    #pragma unroll
    for (int q=0;q<4;q++) acc[q]=0.f;
    for (int i=0;i<24;i++){
      int k8=i*64+j*8;
      const float* zp = (k8<512)? ah+k8 : (k8<1024)? cx+(k8-512) : dhr+(k8-1024);
      float z[8]; ld8f(zp,z);
      #pragma unroll
      for (int g=0;g<4;g++){
        int row = g*HID + cell;
        const float* wp = (k8<1024) ? (dwih + (size_t)row*1024 + k8)
                                    : (dwhh + (size_t)row*HID + (k8-1024));
        float wv[8]; ld8f(wp,wv);
        acc[g] += dot8(wv,z);
      }
    }
    #pragma unroll
    for (int q=0;q<4;q++){
      acc[q] += __shfl_xor(acc[q],1);
      acc[q] += __shfl_xor(acc[q],2);
      acc[q] += __shfl_xor(acc[q],4);
    }
    if (j==0){
      float g0=acc[0]+dbih[0*HID+cell]+dbhh[0*HID+cell];
      float g1=acc[1]+dbih[1*HID+cell]+dbhh[1*HID+cell];
      float g2=acc[2]+dbih[2*HID+cell]+dbhh[2*HID+cell];
      float g3=acc[3]+dbih[3*HID+cell]+dbhh[3*HID+cell];
      float c2 = sigm(g1)*DC[b*HID+cell] + sigm(g0)*tanhfast(g2);
      DC[b*HID+cell]=c2;
      DHw[b*HID+cell]=sigm(g3)*tanhfast(c2);
    }
  } else {
    // conv + fc (+PM) -> PML for step t+1 (uses W(t), WCUM(t))
    if (t+1>=TD) return;
    int idx = blk-1024;
    int b = idx>>3, s8 = idx&7;
    int tb = s8*75;
    __shared__ __align__(16) float wp_[112], wc_[112];
    __shared__ __align__(16) float cw0[32*31], cw1[32*31];
    __shared__ __align__(16) float cb[75*32];
    __shared__ __align__(16) float fcs[128*33];
    if (tid<105){
      int g = tb-15+tid;
      bool ok = (g>=0 && g<TE);
      wp_[tid] = ok ? W[(size_t)b*TE+g] : 0.f;
      wc_[tid] = ok ? WCUM[(size_t)b*TE+g] : 0.f;
    }
    for (int i=tid;i<32*31;i+=256){
      int c=i/31, k=i-c*31;
      cw0[i] = convw[c*62 + k];
      cw1[i] = convw[c*62 + 31 + k];
    }
    for (int i=tid;i<128*33;i+=256){
      int a=i/33, c=i-a*33;
      fcs[i] = (c<32)? fcw[a*32+c] : 0.f;
    }
    __syncthreads();
    for (int i=tid;i<75*32;i+=256){
      int tt=i>>5, c=i&31;
      float s=0.f;
      for (int k=0;k<LK;k++)
        s += cw0[c*31+k]*wp_[tt+k] + cw1[c*31+k]*wc_[tt+k];
      cb[tt*32+c]=s;
    }
    __syncthreads();
    {
      int lane = tid&63, tl = tid>>6;
      int a0 = 2*lane;
      for (int tt=tl; tt<75; tt+=4){
        float l0=0.f, l1=0.f;
        const float* cbr = cb + tt*32;
        #pragma unroll
        for (int c=0;c<32;c++){
          float cv = cbr[c];
          l0 += fcs[a0*33+c]*cv;
          l1 += fcs[(a0+1)*33+c]*cv;
        }
        size_t off = ((size_t)b*TE + tb + tt)*ATTD + a0;
        PML[off]   = __float2bfloat16(l0 + b2f(PM[off]));
        PML[off+1] = __float2bfloat16(l1 + b2f(PM[off+1]));
      }
    }
  }
}

// ---------------- final-step mel -----------------
__global__ __launch_bounds__(256) void k_melfinal(const float* __restrict__ DH,
    const float* __restrict__ CTX, const float* __restrict__ projw, float* __restrict__ MEL)
{
  int gid=blockIdx.x*256+threadIdx.x;
  if (gid>=NB*TGT) return;
  int o=gid%TGT, b=gid/TGT;
  const float* pw=projw+(size_t)o*1024;
  float a=0.f;
  for (int k=0;k<HID;k+=8){
    float wv[8]; ld8f(pw+k,wv);
    a += dot8(wv, DH + b*HID + k);
  }
  for (int k=0;k<HID;k+=8){
    float wv[8]; ld8f(pw+512+k,wv);
    a += dot8(wv, CTX + b*HID + k);
  }
  MEL[((size_t)b*TD+599)*TGT+o]=a;
}

// ---------------- postnet conv (generic, bf16 internal activations) --------
__global__ __launch_bounds__(256) void k_conv(
    const void* __restrict__ inv_, bf16* __restrict__ out,
    const float* __restrict__ w, const float* __restrict__ bias,
    int IC, int OC, int mel_in, int do_tanh, int b0)
{
  __shared__ __align__(16) float xs[256*36];
  int bl=blockIdx.x, bg=b0+bl, oct=blockIdx.y, t0=blockIdx.z*32, tid=threadIdx.x;
  int oc = oct*256 + tid;
  float acc[32];
  #pragma unroll
  for (int q=0;q<32;q++) acc[q]=0.f;
  int nch=(IC+255)/256;
  const float* inf_ = (const float*)inv_;
  const bf16*  inb_ = (const bf16*)inv_;
  for (int ch=0;ch<nch;ch++){
    int icb=ch*256, icn=min(256,IC-icb);
    __syncthreads();
    for (int i=tid;i<icn*36;i+=256){
      int icl=i/36, tt=i-icl*36;
      int tg=t0+tt-2;
      float v=0.f;
      if (tg>=0 && tg<TD){
        int ic=icb+icl;
        v = mel_in ? inf_[((size_t)bg*TD+tg)*TGT+ic]
                   : b2f(inb_[((size_t)bl*IC+ic)*TD+tg]);
      }
      xs[i]=v;
    }
    __syncthreads();
    if (oc<OC){
      const float* wp = w + ((size_t)oc*IC+icb)*5;
      for (int ic=0;ic<icn;ic++){
        float xw[36];
        #pragma unroll
        for (int q=0;q<9;q++) ((float4*)xw)[q]=((const float4*)(xs+ic*36))[q];
        float wk0=wp[ic*5  ],wk1=wp[ic*5+1],wk2=wp[ic*5+2],
              wk3=wp[ic*5+3],wk4=wp[ic*5+4];
        #pragma unroll
        for (int tt=0;tt<32;tt++)
          acc[tt] += wk0*xw[tt]+wk1*xw[tt+1]+wk2*xw[tt+2]+wk3*xw[tt+3]+wk4*xw[tt+4];
      }
    }
  }
  if (oc<OC){
    float bv=bias[oc];
    for (int tt=0;tt<32;tt++){
      int tg=t0+tt;
      if (tg<TD){
        float v=acc[tt]+bv;
        if (do_tanh) v=tanhfast(v);
        out[((size_t)bl*OC+oc)*TD+tg]=__float2bfloat16(v);
      }
    }
  }
}

// ---------------- postnet last layer + in-place residual on d_out ----------
__global__ __launch_bounds__(256) void k_conv_last(
    const bf16* __restrict__ in, const float* __restrict__ w,
    const float* __restrict__ bias, float* __restrict__ outp, int b0)
{
  __shared__ __align__(16) float xs[256*36];
  int bl=blockIdx.x, bg=b0+bl, t0=blockIdx.z*32, tid=threadIdx.x;
  int oc = tid;
  float acc[32];
  #pragma unroll
  for (int q=0;q<32;q++) acc[q]=0.f;
  for (int ch=0;ch<2;ch++){
    int icb=ch*256;
    __syncthreads();
    for (int i=tid;i<256*36;i+=256){
      int icl=i/36, tt=i-icl*36;
      int tg=t0+tt-2;
      float v=0.f;
      if (tg>=0 && tg<TD){
        int ic=icb+icl;
        v = b2f(in[((size_t)bl*PH+ic)*TD+tg]);
      }
      xs[i]=v;
    }
    __syncthreads();
    if (oc<TGT){
      const float* wp = w + ((size_t)oc*PH+icb)*5;
      for (int ic=0;ic<256;ic++){
        float xw[36];
        #pragma unroll
        for (int q=0;q<9;q++) ((float4*)xw)[q]=((const float4*)(xs+ic*36))[q];
        float wk0=wp[ic*5  ],wk1=wp[ic*5+1],wk2=wp[ic*5+2],
              wk3=wp[ic*5+3],wk4=wp[ic*5+4];
        #pragma unroll
        for (int tt=0;tt<32;tt++)
          acc[tt] += wk0*xw[tt]+wk1*xw[tt+1]+wk2*xw[tt+2]+wk3*xw[tt+3]+wk4*xw[tt+4];
      }
    }
  }
  if (oc<TGT){
    float bv=bias[oc];
    for (int tt=0;tt<32;tt++){
      int tg=t0+tt;
      if (tg<TD){
        size_t idx=((size_t)bg*TD+tg)*TGT+oc;
        outp[idx]=acc[tt]+bv+outp[idx];
      }
    }
  }
}

extern "C" void kernel_launch(void* const* d_in, const int* in_sizes, int n_in,
                              void* d_out, int out_size, void* d_ws, size_t ws_size,
                              hipStream_t stream)
{
  const float* enc =(const float*)d_in[0];
  const float* dec =(const float*)d_in[1];
  const float* pw1 =(const float*)d_in[2];  const float* pb1=(const float*)d_in[3];
  const float* pw2 =(const float*)d_in[4];  const float* pb2=(const float*)d_in[5];
  const float* awih=(const float*)d_in[6];  const float* awhh=(const float*)d_in[7];
  const float* abih=(const float*)d_in[8];  const float* abhh=(const float*)d_in[9];
  const float* dwih=(const float*)d_in[10]; const float* dwhh=(const float*)d_in[11];
  const float* dbih=(const float*)d_in[12]; const float* dbhh=(const float*)d_in[13];
  const float* memw=(const float*)d_in[14]; const float* memb=(const float*)d_in[15];
  const float* qw  =(const float*)d_in[16];
  const float* lcw =(const float*)d_in[17];
  const float* lfw =(const float*)d_in[18];
  const float* vw  =(const float*)d_in[19];
  const float* pjw =(const float*)d_in[20];
  const float* cwt0=(const float*)d_in[21]; const float* cbt0=(const float*)d_in[22];
  const float* cwt1=(const float*)d_in[23]; const float* cbt1=(const float*)d_in[24];
  const float* cwt2=(const float*)d_in[25]; const float* cbt2=(const float*)d_in[26];
  const float* cwt3=(const float*)d_in[27]; const float* cbt3=(const float*)d_in[28];
  const float* cwt4=(const float*)d_in[29]; const float* cbt4=(const float*)d_in[30];
  float* MEL = (float*)d_out;
  (void)in_sizes; (void)n_in; (void)out_size; (void)ws_size;

  // ---- workspace layout (~20.4 MB) ----
  char* base=(char*)d_ws;
  const size_t XS_B = (size_t)TD*NB*PREN*2;   //  9,830,400 B
  const size_t PM_B = (size_t)NB*TE*ATTD*2;   //  4,915,200 B
  const size_t HB   = (size_t)NB*HID*4;       //     65,536 B
  const size_t WB   = (size_t)NB*TE*4;        //     76,800 B
  bf16* XSb = (bf16*)base;
  bf16* PMb = (bf16*)(base + XS_B);
  char* sbase = base + XS_B + PM_B;
  float* AHb[2], *DHb[2], *CTXb[2];
  AHb[0] =(float*)(sbase+0*HB);
  AHb[1] =(float*)(sbase+1*HB);
  float* ACb =(float*)(sbase+2*HB);
  DHb[0] =(float*)(sbase+3*HB);
  DHb[1] =(float*)(sbase+4*HB);
  float* DCb =(float*)(sbase+5*HB);
  CTXb[0]=(float*)(sbase+6*HB);
  CTXb[1]=(float*)(sbase+7*HB);
  float* Wb  =(float*)(sbase+8*HB);
  float* WC  =(float*)(sbase+8*HB+WB);
  bf16*  PMLb=(bf16*)(sbase+8*HB+2*WB);
  const int G = 8;
  const size_t PBc_B = (size_t)G*PH*TD*2;
  bf16* PB0 = (bf16*)base;
  bf16* PB1 = (bf16*)(base + PBc_B);

  hipMemsetAsync(sbase, 0, 8*HB+2*WB, stream);

  k_prenet<<<TD,256,0,stream>>>(dec,pw1,pb1,pw2,pb2,XSb);
  k_procmem<<<TE,256,0,stream>>>(enc,memw,memb,PMb);

  // prologue: lstmA(0) + PML(0) (= PM, since conv of zero W/WCUM is zero)
  k_ea<<<1280,256,0,stream>>>(XSb, CTXb[1], AHb[1], AHb[0], ACb,
                              DHb[0], DHb[1], DCb, Wb, WC, lcw, lfw, PMb, PMLb,
                              awih,awhh,abih,abhh,dwih,dwhh,dbih,dbhh, -1);
  for (int t=0;t<TD;t++){
    float* AHt  = AHb[t&1];        // AH(t)
    float* AHw  = AHb[(t+1)&1];    // AH(t+1)
    float* DHp  = DHb[(t+1)&1];    // DH(t-1)
    float* DHw  = DHb[t&1];        // DH(t)
    float* CTXt = CTXb[t&1];       // CTX(t)
    float* CTXp = CTXb[(t+1)&1];   // CTX(t-1)
    k_bc<<<160,256,0,stream>>>(AHt, PMLb, enc, qw, vw,
                               Wb, WC, CTXt, DHp, CTXp, pjw, MEL, t);
    k_ea<<<1280,256,0,stream>>>(XSb, CTXt, AHt, AHw, ACb,
                                DHp, DHw, DCb, Wb, WC, lcw, lfw, PMb, PMLb,
                                awih,awhh,abih,abhh,dwih,dwhh,dbih,dbhh, t);
  }
  // DH(599)=DHb[1], CTX(599)=CTXb[1]
  k_melfinal<<<10,256,0,stream>>>(DHb[1],CTXb[1],pjw,MEL);

  // postnet in 4 batch-chunks of G=8 (buffers fit the dead XS region)
  for (int c=0;c<NB/G;c++){
    int b0=c*G;
    k_conv<<<dim3(G,2,19),256,0,stream>>>(MEL,PB0,cwt0,cbt0,TGT,PH,1,1,b0);
    k_conv<<<dim3(G,2,19),256,0,stream>>>(PB0,PB1,cwt1,cbt1,PH,PH,0,1,b0);
    k_conv<<<dim3(G,2,19),256,0,stream>>>(PB1,PB0,cwt2,cbt2,PH,PH,0,1,b0);
    k_conv<<<dim3(G,2,19),256,0,stream>>>(PB0,PB1,cwt3,cbt3,PH,PH,0,1,b0);
    k_conv_last<<<dim3(G,1,19),256,0,stream>>>(PB1,cwt4,cbt4,MEL,b0);
  }
}

// Round 11
// 58276.379 us; speedup vs baseline: 1.0855x; 1.0160x over previous
//
#include <hip/hip_runtime.h>
#include <hip/hip_bf16.h>

typedef __hip_bfloat16 bf16;

#define NB   32
#define TE   600
#define TD   600
#define TGT  80
#define PREN 256
#define HID  512
#define ATTD 128
#define LF   32
#define LK   31
#define PH   512

__device__ __forceinline__ float b2f(bf16 x){ return __bfloat162float(x); }

__device__ __forceinline__ void ld8bf(const bf16* p, float* o){
  const uint4 u = *(const uint4*)p;
  o[0]=__uint_as_float(u.x<<16); o[1]=__uint_as_float(u.x&0xFFFF0000u);
  o[2]=__uint_as_float(u.y<<16); o[3]=__uint_as_float(u.y&0xFFFF0000u);
  o[4]=__uint_as_float(u.z<<16); o[5]=__uint_as_float(u.z&0xFFFF0000u);
  o[6]=__uint_as_float(u.w<<16); o[7]=__uint_as_float(u.w&0xFFFF0000u);
}

__device__ __forceinline__ void ld8f(const float* p, float* o){
  float4 a=*(const float4*)p, b=*(const float4*)(p+4);
  o[0]=a.x;o[1]=a.y;o[2]=a.z;o[3]=a.w;
  o[4]=b.x;o[5]=b.y;o[6]=b.z;o[7]=b.w;
}

__device__ __forceinline__ float dot8(const float* w, const float* z){
  return w[0]*z[0]+w[1]*z[1]+w[2]*z[2]+w[3]*z[3]
       + w[4]*z[4]+w[5]*z[5]+w[6]*z[6]+w[7]*z[7];
}

__device__ __forceinline__ float sigm(float x){ return 1.f/(1.f+__expf(-x)); }
__device__ __forceinline__ float tanhfast(float x){
  float e = __expf(2.f*x);
  return 1.f - 2.f/(e+1.f);
}

// ---------------- fp32 -> bf16 elementwise (enc copy) -----------------
__global__ __launch_bounds__(256) void k_e2b(const float* __restrict__ s,
    bf16* __restrict__ d, int n)
{
  int i=(blockIdx.x*256+threadIdx.x)*4;
  int stride=gridDim.x*256*4;
  for (; i<n; i+=stride){
    float4 v=*(const float4*)(s+i);
    d[i  ]=__float2bfloat16(v.x);
    d[i+1]=__float2bfloat16(v.y);
    d[i+2]=__float2bfloat16(v.z);
    d[i+3]=__float2bfloat16(v.w);
  }
}

// ---------------- prenet: XS[t][b][256] (bf16) -----------------
__global__ __launch_bounds__(256) void k_prenet(const float* __restrict__ dec,
    const float* __restrict__ w1, const float* __restrict__ b1,
    const float* __restrict__ w2, const float* __restrict__ b2,
    bf16* __restrict__ XS)
{
  int t = blockIdx.x, tid = threadIdx.x;
  __shared__ __align__(16) float fr[NB*TGT];
  __shared__ __align__(16) float h1[NB*PREN];
  for (int i=tid;i<NB*TGT;i+=256){
    int b=i/TGT,c=i%TGT;
    fr[b*TGT+c] = (t==0)?0.f:dec[((size_t)b*TD+(t-1))*TGT+c];
  }
  __syncthreads();
  {
    int oc=tid; float bb=b1[oc];
    const float* wr = w1 + (size_t)oc*TGT;
    for (int b=0;b<NB;b++){
      float acc=bb;
      for (int k=0;k<TGT;k+=8){
        float wv[8]; ld8f(wr+k,wv);
        acc += dot8(wv, fr + b*TGT + k);
      }
      h1[b*PREN+oc]=fmaxf(acc,0.f);
    }
  }
  __syncthreads();
  {
    int oc=tid; float bb=b2[oc];
    const float* wr = w2 + (size_t)oc*PREN;
    for (int b=0;b<NB;b++){
      float acc=bb;
      for (int k=0;k<PREN;k+=8){
        float wv[8]; ld8f(wr+k,wv);
        acc += dot8(wv, h1 + b*PREN + k);
      }
      XS[((size_t)t*NB+b)*PREN+oc]=__float2bfloat16(fmaxf(acc,0.f));
    }
  }
}

// ---------------- proc_mem: PM[b][t][128] (bf16) -----------------
__global__ __launch_bounds__(256) void k_procmem(const float* __restrict__ enc,
    const float* __restrict__ mw, const float* __restrict__ mb, bf16* __restrict__ PM)
{
  int t=blockIdx.x, tid=threadIdx.x;
  __shared__ __align__(16) float xe[16*HID];
  int a = tid & 127, bh = tid >> 7;
  float bb = mb[a];
  const float* wr = mw + (size_t)a*HID;
  for (int half=0; half<2; half++){
    __syncthreads();
    for (int i=tid;i<16*HID;i+=256){
      int bl=i>>9, h=i&511;
      xe[i] = enc[((size_t)(half*16+bl)*TE + t)*HID + h];
    }
    __syncthreads();
    for (int bl=bh*8; bl<bh*8+8; bl++){
      float acc=bb;
      for (int k=0;k<HID;k+=8){
        float wv[8]; ld8f(wr+k,wv);
        acc += dot8(wv, xe + bl*HID + k);
      }
      PM[((size_t)(half*16+bl)*TE + t)*ATTD + a] = __float2bfloat16(acc);
    }
  }
}

// ---------------- phase BC: E + softmax + ctx + mel(t-1), 512 threads -----
// grid 96: blk<64: (b=blk>>1, k2=blk&1) E(2-way redundant)+softmax+256h ctx
//          blk in [64,96): mel block, b = blk-64
// EB=1: ctx reads bf16 ENCB; EB=0: ctx reads fp32 enc.
template<int EB>
__global__ __launch_bounds__(512) void k_bc(
    const float* __restrict__ AH, const bf16* __restrict__ PML,
    const float* __restrict__ enc, const bf16* __restrict__ encb,
    const float* __restrict__ qw, const float* __restrict__ vw,
    float* __restrict__ W, float* __restrict__ WCUM, float* __restrict__ CTXw,
    const float* __restrict__ DHp, const float* __restrict__ CTXp,
    const float* __restrict__ projw, float* __restrict__ MEL, int t)
{
  int blk=blockIdx.x, tid=threadIdx.x;
  if (blk>=64){
    // ---- mel(t-1): reads DH(t-1), CTX(t-1) (both stable this phase) ----
    if (t==0 || tid>=256) return;
    int b = blk-64;
    const float* dh = DHp + b*HID;
    const float* c2 = CTXp + b*HID;
    #pragma unroll
    for (int pass=0; pass<3; ++pass){
      int o = pass*32 + (tid>>3);
      if (o<TGT){
        int j = tid&7;
        const float* pw = projw + (size_t)o*1024;
        float a=0.f;
        for (int i=0;i<16;i++){
          int k = j*128 + i*8;
          const float* zp = (k<512)? dh+k : c2+(k-512);
          float z[8]; ld8f(zp,z);
          float wv[8]; ld8f(pw+k,wv);
          a += dot8(wv,z);
        }
        a += __shfl_xor(a,1); a += __shfl_xor(a,2); a += __shfl_xor(a,4);
        if (j==0) MEL[((size_t)b*TD + (t-1))*TGT + o] = a;
      }
    }
    return;
  }
  int b = blk>>1, k2 = blk&1;
  __shared__ float qs[128], vv[128];
  __shared__ __align__(16) float el[608], wl[608];
  __shared__ __align__(16) float part[4096];   // 16 KB scratch (both paths)
  __shared__ float red[8];
  // q-projection: 4-way split-K over all 512 threads (a=tid>>2, kl=tid&3)
  {
    if (tid<128) vv[tid]=vw[tid];
    int a = tid>>2, kl = tid&3;
    const float* qr = qw + (size_t)a*HID + kl*128;
    const float* ah = AH + b*HID + kl*128;
    float acc = 0.f;
    for (int i=0;i<16;i++){
      float wv2[8]; ld8f(qr+i*8,wv2);
      acc += dot8(wv2, ah+i*8);
    }
    acc += __shfl_xor(acc,1);
    acc += __shfl_xor(acc,2);
    if (kl==0) qs[a]=acc;
  }
  __syncthreads();
  // thread-parallel E assembly: each thread owns t' rows (full 128-dot each)
  for (int r=0;r<2;r++){
    int tt=tid+r*512;
    if (tt<TE){
      const uint4* pm4=(const uint4*)(PML+((size_t)b*TE+tt)*ATTD);
      float s=0.f;
      #pragma unroll 4
      for (int g=0;g<16;g++){
        uint4 um=pm4[g];
        unsigned mm[4]={um.x,um.y,um.z,um.w};
        #pragma unroll
        for (int q=0;q<4;q++){
          int a=g*8+q*2;
          float x0=qs[a]  +__uint_as_float(mm[q]<<16);
          float x1=qs[a+1]+__uint_as_float(mm[q]&0xFFFF0000u);
          s+=vv[a]*tanhfast(x0)+vv[a+1]*tanhfast(x1);
        }
      }
      el[tt]=s;
    }
  }
  __syncthreads();
  // softmax over el[0..599] (512 threads, 8 waves)
  float e0[2]; float mx=-1e30f;
  #pragma unroll
  for (int r=0;r<2;r++){
    int i=tid+r*512;
    float v=(i<TE)? el[i] : -1e30f;
    e0[r]=v; mx=fmaxf(mx,v);
  }
  for (int off=1;off<64;off<<=1) mx=fmaxf(mx,__shfl_xor(mx,off));
  if ((tid&63)==0) red[tid>>6]=mx;
  __syncthreads();
  float m=-1e30f;
  #pragma unroll
  for (int k=0;k<8;k++) m=fmaxf(m,red[k]);
  float ex[2]; float s=0.f;
  #pragma unroll
  for (int r=0;r<2;r++){
    int i=tid+r*512;
    ex[r]=(i<TE)? __expf(e0[r]-m) : 0.f;
    s+=ex[r];
  }
  for (int off=1;off<64;off<<=1) s+=__shfl_xor(s,off);
  __syncthreads();
  if ((tid&63)==0) red[tid>>6]=s;
  __syncthreads();
  float sum=0.f;
  #pragma unroll
  for (int k=0;k<8;k++) sum+=red[k];
  float inv=1.f/sum;
  #pragma unroll
  for (int r=0;r<2;r++){
    int i=tid+r*512;
    if (i<TE){
      float w2=ex[r]*inv;
      wl[i]=w2;
      if (k2==0){
        W[(size_t)b*TE+i]=w2;
        WCUM[(size_t)b*TE+i]+=w2;
      }
    }
  }
  __syncthreads();
  // ctx slice: h in [k2*256, k2*256+256)
  if (EB){
    int g = tid&31, tl = tid>>5;           // 32 groups x 8 bf16 h, 16 t-lanes
    const bf16* ep = encb + ((size_t)b*TE)*HID + k2*256 + g*8;
    float acc[8];
    #pragma unroll
    for (int e=0;e<8;e++) acc[e]=0.f;
    for (int u=0;u<38;u++){
      int tt = tl + u*16;
      if (tt<TE){
        float w = wl[tt];
        float z[8]; ld8bf(ep + (size_t)tt*HID, z);
        #pragma unroll
        for (int e=0;e<8;e++) acc[e] += w*z[e];
      }
    }
    #pragma unroll
    for (int e=0;e<8;e++) part[tid*8+e]=acc[e];
  } else {
    int g = tid&63, tl = tid>>6;           // 64 groups x 4 fp32 h, 8 t-lanes
    const float4* ep4 = (const float4*)(enc + ((size_t)b*TE)*HID + k2*256 + g*4);
    float4 acc; acc.x=0.f; acc.y=0.f; acc.z=0.f; acc.w=0.f;
    for (int u=0;u<75;u++){
      int tt = tl + u*8;
      float w = wl[tt];
      float4 e = ep4[(size_t)tt*(HID/4)];
      acc.x += w*e.x; acc.y += w*e.y; acc.z += w*e.z; acc.w += w*e.w;
    }
    ((float4*)part)[tid]=acc;
  }
  __syncthreads();
  if (tid<256){
    float sH=0.f;
    if (EB){
      int gh = tid>>3, e = tid&7;
      #pragma unroll
      for (int tl=0;tl<16;tl++) sH += part[(tl*32+gh)*8 + e];
    } else {
      int gh = tid>>2, e = tid&3;
      #pragma unroll
      for (int tl=0;tl<8;tl++) sH += part[(tl*64+gh)*4 + e];
    }
    CTXw[b*HID + k2*256 + tid] = sH;
  }
}

// ---------------- phase EA: lstmA(t+1) || lstmD(t) || conv+fc -> PML(t+1) --
// blocks [0,512): lstmA(t+1), cell=blk; [512,1024): lstmD(t), cell=blk-512;
// [1024,1280): conv+fc, idx=blk-1024: b=idx>>3, s8=idx&7 (75 t' each)
__global__ __launch_bounds__(256) void k_ea(
    const bf16* __restrict__ XS,
    const float* __restrict__ CTXt, const float* __restrict__ AHt,
    float* __restrict__ AHw, float* __restrict__ AC,
    const float* __restrict__ DHp, float* __restrict__ DHw, float* __restrict__ DC,
    const float* __restrict__ W, const float* __restrict__ WCUM,
    const float* __restrict__ convw, const float* __restrict__ fcw,
    const bf16* __restrict__ PM, bf16* __restrict__ PML,
    const float* __restrict__ awih, const float* __restrict__ awhh,
    const float* __restrict__ abih, const float* __restrict__ abhh,
    const float* __restrict__ dwih, const float* __restrict__ dwhh,
    const float* __restrict__ dbih, const float* __restrict__ dbhh,
    int t)
{
  int blk=blockIdx.x, tid=threadIdx.x;
  if (blk<512){
    int s = t+1;
    if (s>=TD) return;
    int b=tid>>3, j=tid&7;
    int cell = blk;
    const bf16* xs = XS + ((size_t)s*NB+b)*PREN;
    const float* cx = CTXt + b*HID;
    const float* hr = AHt + b*HID;
    float acc[4];
    #pragma unroll
    for (int q=0;q<4;q++) acc[q]=0.f;
    for (int i=0;i<20;i++){
      int k8=i*64+j*8;
      float z[8];
      if (k8<256) ld8bf(xs+k8,z);
      else ld8f((k8<768)? cx+(k8-256) : hr+(k8-768), z);
      #pragma unroll
      for (int g=0;g<4;g++){
        int row = g*HID + cell;
        const float* wp = (k8<768) ? (awih + (size_t)row*768 + k8)
                                   : (awhh + (size_t)row*HID + (k8-768));
        float wv[8]; ld8f(wp,wv);
        acc[g] += dot8(wv,z);
      }
    }
    #pragma unroll
    for (int q=0;q<4;q++){
      acc[q] += __shfl_xor(acc[q],1);
      acc[q] += __shfl_xor(acc[q],2);
      acc[q] += __shfl_xor(acc[q],4);
    }
    if (j==0){
      float g0=acc[0]+abih[0*HID+cell]+abhh[0*HID+cell];
      float g1=acc[1]+abih[1*HID+cell]+abhh[1*HID+cell];
      float g2=acc[2]+abih[2*HID+cell]+abhh[2*HID+cell];
      float g3=acc[3]+abih[3*HID+cell]+abhh[3*HID+cell];
      float c2 = sigm(g1)*AC[b*HID+cell] + sigm(g0)*tanhfast(g2);
      AC[b*HID+cell]=c2;
      AHw[b*HID+cell]=sigm(g3)*tanhfast(c2);
    }
  } else if (blk<1024){
    if (t<0) return;
    int b=tid>>3, j=tid&7;
    int cell = blk-512;
    const float* ah  = AHt + b*HID;
    const float* cx  = CTXt + b*HID;
    const float* dhr = DHp + b*HID;
    float acc[4];
    #pragma unroll
    for (int q=0;q<4;q++) acc[q]=0.f;
    for (int i=0;i<24;i++){
      int k8=i*64+j*8;
      const float* zp = (k8<512)? ah+k8 : (k8<1024)? cx+(k8-512) : dhr+(k8-1024);
      float z[8]; ld8f(zp,z);
      #pragma unroll
      for (int g=0;g<4;g++){
        int row = g*HID + cell;
        const float* wp = (k8<1024) ? (dwih + (size_t)row*1024 + k8)
                                    : (dwhh + (size_t)row*HID + (k8-1024));
        float wv[8]; ld8f(wp,wv);
        acc[g] += dot8(wv,z);
      }
    }
    #pragma unroll
    for (int q=0;q<4;q++){
      acc[q] += __shfl_xor(acc[q],1);
      acc[q] += __shfl_xor(acc[q],2);
      acc[q] += __shfl_xor(acc[q],4);
    }
    if (j==0){
      float g0=acc[0]+dbih[0*HID+cell]+dbhh[0*HID+cell];
      float g1=acc[1]+dbih[1*HID+cell]+dbhh[1*HID+cell];
      float g2=acc[2]+dbih[2*HID+cell]+dbhh[2*HID+cell];
      float g3=acc[3]+dbih[3*HID+cell]+dbhh[3*HID+cell];
      float c2 = sigm(g1)*DC[b*HID+cell] + sigm(g0)*tanhfast(g2);
      DC[b*HID+cell]=c2;
      DHw[b*HID+cell]=sigm(g3)*tanhfast(c2);
    }
  } else {
    // conv + fc (+PM) -> PML for step t+1 (uses W(t), WCUM(t))
    if (t+1>=TD) return;
    int idx = blk-1024;
    int b = idx>>3, s8 = idx&7;
    int tb = s8*75;
    __shared__ __align__(16) float wp_[112], wc_[112];
    __shared__ __align__(16) float cw0[32*31], cw1[32*31];
    __shared__ __align__(16) float cb[75*32];
    __shared__ __align__(16) float fcs[128*33];
    if (tid<105){
      int g = tb-15+tid;
      bool ok = (g>=0 && g<TE);
      wp_[tid] = ok ? W[(size_t)b*TE+g] : 0.f;
      wc_[tid] = ok ? WCUM[(size_t)b*TE+g] : 0.f;
    }
    for (int i=tid;i<32*31;i+=256){
      int c=i/31, k=i-c*31;
      cw0[i] = convw[c*62 + k];
      cw1[i] = convw[c*62 + 31 + k];
    }
    for (int i=tid;i<128*33;i+=256){
      int a=i/33, c=i-a*33;
      fcs[i] = (c<32)? fcw[a*32+c] : 0.f;
    }
    __syncthreads();
    for (int i=tid;i<75*32;i+=256){
      int tt=i>>5, c=i&31;
      float s=0.f;
      for (int k=0;k<LK;k++)
        s += cw0[c*31+k]*wp_[tt+k] + cw1[c*31+k]*wc_[tt+k];
      cb[tt*32+c]=s;
    }
    __syncthreads();
    {
      int lane = tid&63, tl = tid>>6;
      int a0 = 2*lane;
      for (int tt=tl; tt<75; tt+=4){
        float l0=0.f, l1=0.f;
        const float* cbr = cb + tt*32;
        #pragma unroll
        for (int c=0;c<32;c++){
          float cv = cbr[c];
          l0 += fcs[a0*33+c]*cv;
          l1 += fcs[(a0+1)*33+c]*cv;
        }
        size_t off = ((size_t)b*TE + tb + tt)*ATTD + a0;
        PML[off]   = __float2bfloat16(l0 + b2f(PM[off]));
        PML[off+1] = __float2bfloat16(l1 + b2f(PM[off+1]));
      }
    }
  }
}

// ---------------- final-step mel -----------------
__global__ __launch_bounds__(256) void k_melfinal(const float* __restrict__ DH,
    const float* __restrict__ CTX, const float* __restrict__ projw, float* __restrict__ MEL)
{
  int gid=blockIdx.x*256+threadIdx.x;
  if (gid>=NB*TGT) return;
  int o=gid%TGT, b=gid/TGT;
  const float* pw=projw+(size_t)o*1024;
  float a=0.f;
  for (int k=0;k<HID;k+=8){
    float wv[8]; ld8f(pw+k,wv);
    a += dot8(wv, DH + b*HID + k);
  }
  for (int k=0;k<HID;k+=8){
    float wv[8]; ld8f(pw+512+k,wv);
    a += dot8(wv, CTX + b*HID + k);
  }
  MEL[((size_t)b*TD+599)*TGT+o]=a;
}

// ---------------- postnet conv (generic, bf16 internal activations) --------
__global__ __launch_bounds__(256) void k_conv(
    const void* __restrict__ inv_, bf16* __restrict__ out,
    const float* __restrict__ w, const float* __restrict__ bias,
    int IC, int OC, int mel_in, int do_tanh, int b0)
{
  __shared__ __align__(16) float xs[256*36];
  int bl=blockIdx.x, bg=b0+bl, oct=blockIdx.y, t0=blockIdx.z*32, tid=threadIdx.x;
  int oc = oct*256 + tid;
  float acc[32];
  #pragma unroll
  for (int q=0;q<32;q++) acc[q]=0.f;
  int nch=(IC+255)/256;
  const float* inf_ = (const float*)inv_;
  const bf16*  inb_ = (const bf16*)inv_;
  for (int ch=0;ch<nch;ch++){
    int icb=ch*256, icn=min(256,IC-icb);
    __syncthreads();
    for (int i=tid;i<icn*36;i+=256){
      int icl=i/36, tt=i-icl*36;
      int tg=t0+tt-2;
      float v=0.f;
      if (tg>=0 && tg<TD){
        int ic=icb+icl;
        v = mel_in ? inf_[((size_t)bg*TD+tg)*TGT+ic]
                   : b2f(inb_[((size_t)bl*IC+ic)*TD+tg]);
      }
      xs[i]=v;
    }
    __syncthreads();
    if (oc<OC){
      const float* wp = w + ((size_t)oc*IC+icb)*5;
      for (int ic=0;ic<icn;ic++){
        float xw[36];
        #pragma unroll
        for (int q=0;q<9;q++) ((float4*)xw)[q]=((const float4*)(xs+ic*36))[q];
        float wk0=wp[ic*5  ],wk1=wp[ic*5+1],wk2=wp[ic*5+2],
              wk3=wp[ic*5+3],wk4=wp[ic*5+4];
        #pragma unroll
        for (int tt=0;tt<32;tt++)
          acc[tt] += wk0*xw[tt]+wk1*xw[tt+1]+wk2*xw[tt+2]+wk3*xw[tt+3]+wk4*xw[tt+4];
      }
    }
  }
  if (oc<OC){
    float bv=bias[oc];
    for (int tt=0;tt<32;tt++){
      int tg=t0+tt;
      if (tg<TD){
        float v=acc[tt]+bv;
        if (do_tanh) v=tanhfast(v);
        out[((size_t)bl*OC+oc)*TD+tg]=__float2bfloat16(v);
      }
    }
  }
}

// ---------------- postnet last layer + in-place residual on d_out ----------
__global__ __launch_bounds__(256) void k_conv_last(
    const bf16* __restrict__ in, const float* __restrict__ w,
    const float* __restrict__ bias, float* __restrict__ outp, int b0)
{
  __shared__ __align__(16) float xs[256*36];
  int bl=blockIdx.x, bg=b0+bl, t0=blockIdx.z*32, tid=threadIdx.x;
  int oc = tid;
  float acc[32];
  #pragma unroll
  for (int q=0;q<32;q++) acc[q]=0.f;
  for (int ch=0;ch<2;ch++){
    int icb=ch*256;
    __syncthreads();
    for (int i=tid;i<256*36;i+=256){
      int icl=i/36, tt=i-icl*36;
      int tg=t0+tt-2;
      float v=0.f;
      if (tg>=0 && tg<TD){
        int ic=icb+icl;
        v = b2f(in[((size_t)bl*PH+ic)*TD+tg]);
      }
      xs[i]=v;
    }
    __syncthreads();
    if (oc<TGT){
      const float* wp = w + ((size_t)oc*PH+icb)*5;
      for (int ic=0;ic<256;ic++){
        float xw[36];
        #pragma unroll
        for (int q=0;q<9;q++) ((float4*)xw)[q]=((const float4*)(xs+ic*36))[q];
        float wk0=wp[ic*5  ],wk1=wp[ic*5+1],wk2=wp[ic*5+2],
              wk3=wp[ic*5+3],wk4=wp[ic*5+4];
        #pragma unroll
        for (int tt=0;tt<32;tt++)
          acc[tt] += wk0*xw[tt]+wk1*xw[tt+1]+wk2*xw[tt+2]+wk3*xw[tt+3]+wk4*xw[tt+4];
      }
    }
  }
  if (oc<TGT){
    float bv=bias[oc];
    for (int tt=0;tt<32;tt++){
      int tg=t0+tt;
      if (tg<TD){
        size_t idx=((size_t)bg*TD+tg)*TGT+oc;
        outp[idx]=acc[tt]+bv+outp[idx];
      }
    }
  }
}

extern "C" void kernel_launch(void* const* d_in, const int* in_sizes, int n_in,
                              void* d_out, int out_size, void* d_ws, size_t ws_size,
                              hipStream_t stream)
{
  const float* enc =(const float*)d_in[0];
  const float* dec =(const float*)d_in[1];
  const float* pw1 =(const float*)d_in[2];  const float* pb1=(const float*)d_in[3];
  const float* pw2 =(const float*)d_in[4];  const float* pb2=(const float*)d_in[5];
  const float* awih=(const float*)d_in[6];  const float* awhh=(const float*)d_in[7];
  const float* abih=(const float*)d_in[8];  const float* abhh=(const float*)d_in[9];
  const float* dwih=(const float*)d_in[10]; const float* dwhh=(const float*)d_in[11];
  const float* dbih=(const float*)d_in[12]; const float* dbhh=(const float*)d_in[13];
  const float* memw=(const float*)d_in[14]; const float* memb=(const float*)d_in[15];
  const float* qw  =(const float*)d_in[16];
  const float* lcw =(const float*)d_in[17];
  const float* lfw =(const float*)d_in[18];
  const float* vw  =(const float*)d_in[19];
  const float* pjw =(const float*)d_in[20];
  const float* cwt0=(const float*)d_in[21]; const float* cbt0=(const float*)d_in[22];
  const float* cwt1=(const float*)d_in[23]; const float* cbt1=(const float*)d_in[24];
  const float* cwt2=(const float*)d_in[25]; const float* cbt2=(const float*)d_in[26];
  const float* cwt3=(const float*)d_in[27]; const float* cbt3=(const float*)d_in[28];
  const float* cwt4=(const float*)d_in[29]; const float* cbt4=(const float*)d_in[30];
  float* MEL = (float*)d_out;
  (void)in_sizes; (void)n_in; (void)out_size;

  // ---- workspace layout (20.34 MB base; +19.66 MB optional bf16 enc) ----
  char* base=(char*)d_ws;
  const size_t XS_B = (size_t)TD*NB*PREN*2;   //  9,830,400 B
  const size_t PM_B = (size_t)NB*TE*ATTD*2;   //  4,915,200 B
  const size_t HB   = (size_t)NB*HID*4;       //     65,536 B
  const size_t WB   = (size_t)NB*TE*4;        //     76,800 B
  bf16* XSb = (bf16*)base;
  bf16* PMb = (bf16*)(base + XS_B);
  char* sbase = base + XS_B + PM_B;
  float* AHb[2], *DHb[2], *CTXb[2];
  AHb[0] =(float*)(sbase+0*HB);
  AHb[1] =(float*)(sbase+1*HB);
  float* ACb =(float*)(sbase+2*HB);
  DHb[0] =(float*)(sbase+3*HB);
  DHb[1] =(float*)(sbase+4*HB);
  float* DCb =(float*)(sbase+5*HB);
  CTXb[0]=(float*)(sbase+6*HB);
  CTXb[1]=(float*)(sbase+7*HB);
  float* Wb  =(float*)(sbase+8*HB);
  float* WC  =(float*)(sbase+8*HB+WB);
  bf16*  PMLb=(bf16*)(sbase+8*HB+2*WB);
  const size_t BASE_B = XS_B + PM_B + 8*HB + 2*WB + PM_B;  // 20,338,688
  bf16* ENCB = (bf16*)(base + BASE_B);
  const size_t ENC_B = (size_t)NB*TE*HID*2;                // 19,660,800
  const bool useE = (ws_size >= BASE_B + ENC_B);

  const int G = 8;
  const size_t PBc_B = (size_t)G*PH*TD*2;
  bf16* PB0 = (bf16*)base;
  bf16* PB1 = (bf16*)(base + PBc_B);

  hipMemsetAsync(sbase, 0, 8*HB+2*WB, stream);

  if (useE) k_e2b<<<2048,256,0,stream>>>(enc, ENCB, NB*TE*HID);
  k_prenet<<<TD,256,0,stream>>>(dec,pw1,pb1,pw2,pb2,XSb);
  k_procmem<<<TE,256,0,stream>>>(enc,memw,memb,PMb);

  // prologue: lstmA(0) + PML(0) (= PM, since conv of zero W/WCUM is zero)
  k_ea<<<1280,256,0,stream>>>(XSb, CTXb[1], AHb[1], AHb[0], ACb,
                              DHb[0], DHb[1], DCb, Wb, WC, lcw, lfw, PMb, PMLb,
                              awih,awhh,abih,abhh,dwih,dwhh,dbih,dbhh, -1);
  for (int t=0;t<TD;t++){
    float* AHt  = AHb[t&1];        // AH(t)
    float* AHw  = AHb[(t+1)&1];    // AH(t+1)
    float* DHp  = DHb[(t+1)&1];    // DH(t-1)
    float* DHw  = DHb[t&1];        // DH(t)
    float* CTXt = CTXb[t&1];       // CTX(t)
    float* CTXp = CTXb[(t+1)&1];   // CTX(t-1)
    if (useE)
      k_bc<1><<<96,512,0,stream>>>(AHt, PMLb, enc, ENCB, qw, vw,
                                   Wb, WC, CTXt, DHp, CTXp, pjw, MEL, t);
    else
      k_bc<0><<<96,512,0,stream>>>(AHt, PMLb, enc, ENCB, qw, vw,
                                   Wb, WC, CTXt, DHp, CTXp, pjw, MEL, t);
    k_ea<<<1280,256,0,stream>>>(XSb, CTXt, AHt, AHw, ACb,
                                DHp, DHw, DCb, Wb, WC, lcw, lfw, PMb, PMLb,
                                awih,awhh,abih,abhh,dwih,dwhh,dbih,dbhh, t);
  }
  // DH(599)=DHb[1], CTX(599)=CTXb[1]
  k_melfinal<<<10,256,0,stream>>>(DHb[1],CTXb[1],pjw,MEL);

  // postnet in 4 batch-chunks of G=8 (buffers fit the dead XS region)
  for (int c=0;c<NB/G;c++){
    int b0=c*G;
    k_conv<<<dim3(G,2,19),256,0,stream>>>(MEL,PB0,cwt0,cbt0,TGT,PH,1,1,b0);
    k_conv<<<dim3(G,2,19),256,0,stream>>>(PB0,PB1,cwt1,cbt1,PH,PH,0,1,b0);
    k_conv<<<dim3(G,2,19),256,0,stream>>>(PB1,PB0,cwt2,cbt2,PH,PH,0,1,b0);
    k_conv<<<dim3(G,2,19),256,0,stream>>>(PB0,PB1,cwt3,cbt3,PH,PH,0,1,b0);
    k_conv_last<<<dim3(G,1,19),256,0,stream>>>(PB1,cwt4,cbt4,MEL,b0);
  }
}